// Round 16
// baseline (130.752 us; speedup 1.0000x reference)
//
#include <hip/hip_runtime.h>

// VQ-VAE quantizer: x[32][64][64][64] f32 NCHW, embed[1024][64] f32
// out: z_q (8388608 f32, NCHW) ++ loss (1 f32),  loss = 1.25*mean((z_q-z)^2)
//
// R16: occupancy 2x via CODE-QUARTER blocks + global key combine.
//  - vq_sweep: block = 256 thr = 4 waves x 64 pos (nt=4) over ONE code
//    quarter (18 KB LDS codebook via global_load_lds, 72-B stride rows ->
//    conflict-free b64 reads). Grid 2048 = 512 tiles x 4 quarters (adjacent
//    blkIdx = same tile -> x re-reads L2/L3-absorbed, proven R13).
//    launch_bounds(256,8): 8 blocks/CU by LDS -> 32 waves/CU (R8-R15: only
//    occupancy ever moved the needle). Winner published by atomicMax on
//    packed-u32 keys (max = commutative -> deterministic).
//  - vq_out: streaming epilogue (keys -> idx -> gather embed -> 32 MB write,
//    loss acc-part). Decouples the write phase from the sweep.
// acc = fp8(z).(1024e) + 64 - 512||e||^2 in (9,119) > 0; key =
// (bits(acc) & ~1023) | (1023-code): u32 max = argmin dist, smallest-index
// tie-break. dist = ||z||^2 - acc/512 + 0.125. Loss never re-reads x.

#define TOTAL_ELEMS 8388608
#define LOSS_SCALE (1.25f / 8388608.f)
#define ROWB 72   // eb/LDS bytes per codebook row (64 data + 8 pad)

typedef float f32x4 __attribute__((ext_vector_type(4)));

static __device__ __forceinline__ void gload_lds16(const void* g, void* l) {
    __builtin_amdgcn_global_load_lds(
        (const __attribute__((address_space(1))) void*)g,
        (__attribute__((address_space(3))) void*)l,
        16, 0, 0);
}

static __device__ __forceinline__ unsigned int umax(unsigned int a, unsigned int b) {
    return a > b ? a : b;
}

// ---- prep: embed f32 -> fp8 e4m3 (x1024), rows @ 72-B stride; c0; zero loss ----
__global__ void vq_prep(const float* __restrict__ embed,
                        unsigned char* __restrict__ eb,
                        float* __restrict__ c0,
                        float* __restrict__ loss_slot) {
    int t   = blockIdx.x * 256 + threadIdx.x;   // 0..4095
    int row = t >> 2, qd = t & 3;               // qd = k-octet
    const float* s0 = embed + row * 64 + qd * 8;
    const float* s1 = embed + row * 64 + 32 + qd * 8;
    f32x4 v0 = *(const f32x4*)s0, v1 = *(const f32x4*)(s0 + 4);
    f32x4 w0 = *(const f32x4*)s1, w1 = *(const f32x4*)(s1 + 4);
    float s = v0[0]*v0[0] + v0[1]*v0[1] + v0[2]*v0[2] + v0[3]*v0[3]
            + v1[0]*v1[0] + v1[1]*v1[1] + v1[2]*v1[2] + v1[3]*v1[3]
            + w0[0]*w0[0] + w0[1]*w0[1] + w0[2]*w0[2] + w0[3]*w0[3]
            + w1[0]*w1[0] + w1[1]*w1[1] + w1[2]*w1[2] + w1[3]*w1[3];
    unsigned int d0 = 0, d1 = 0, d2 = 0, d3 = 0;
    d0 = __builtin_amdgcn_cvt_pk_fp8_f32(v0[0]*1024.f, v0[1]*1024.f, d0, false);
    d0 = __builtin_amdgcn_cvt_pk_fp8_f32(v0[2]*1024.f, v0[3]*1024.f, d0, true);
    d1 = __builtin_amdgcn_cvt_pk_fp8_f32(v1[0]*1024.f, v1[1]*1024.f, d1, false);
    d1 = __builtin_amdgcn_cvt_pk_fp8_f32(v1[2]*1024.f, v1[3]*1024.f, d1, true);
    d2 = __builtin_amdgcn_cvt_pk_fp8_f32(w0[0]*1024.f, w0[1]*1024.f, d2, false);
    d2 = __builtin_amdgcn_cvt_pk_fp8_f32(w0[2]*1024.f, w0[3]*1024.f, d2, true);
    d3 = __builtin_amdgcn_cvt_pk_fp8_f32(w1[0]*1024.f, w1[1]*1024.f, d3, false);
    d3 = __builtin_amdgcn_cvt_pk_fp8_f32(w1[2]*1024.f, w1[3]*1024.f, d3, true);
    unsigned long long g0 = (unsigned long long)d0 | ((unsigned long long)d1 << 32);
    unsigned long long g1 = (unsigned long long)d2 | ((unsigned long long)d3 << 32);
    char* rb = (char*)eb + row * ROWB;
    *(unsigned long long*)(rb + qd * 8)      = g0;   // k[qd*8..+8]
    *(unsigned long long*)(rb + 32 + qd * 8) = g1;   // k[32+qd*8..+8]
    s += __shfl_xor(s, 1);
    s += __shfl_xor(s, 2);
    if (qd == 0) c0[row] = 64.f - 512.f * s;
    if (t == 0) *loss_slot = 0.f;
}

// ---- sweep: block = 256 thr = 4 waves x 64 pos (nt=4), one code quarter ----
// grid 2048 = 512 tiles x 4 quarters (quarter = blk&3, adjacent -> co-resident)
__global__ __launch_bounds__(256, 8) void vq_sweep(
    const float* __restrict__ x,
    const unsigned char* __restrict__ eb,       // fp8 rows @ 72-B stride
    const float* __restrict__ c0,
    unsigned int* __restrict__ keys,            // [131072], pre-zeroed
    float* __restrict__ loss) {

    __shared__ __align__(16) unsigned char cb[256 * ROWB]; // 18 KB quarter
    __shared__ __align__(16) float c0l[256];

    const int t    = threadIdx.x;
    const int wv   = t >> 6, lane = t & 63;
    const int l15  = lane & 15, lq = lane >> 4;

    const int blk  = blockIdx.x;                 // 0..2047
    const int q    = blk & 3;                    // code quarter
    const int tile = blk >> 2;                   // 0..511
    const int b    = tile >> 4;
    const int h0   = (tile & 15) * 4;
    const size_t xbase = (size_t)b * 262144 + (size_t)h0 * 64;

    // ---- quarter codebook DMA (18432 B linear, async, no VGPRs) ----
    const char* ebq = (const char*)eb + q * (256 * ROWB);
#pragma unroll
    for (int s = 0; s < 4; s++)
        gload_lds16(ebq + s * 4096 + t * 16, &cb[s * 4096 + t * 16]);
    if (t < 128)
        gload_lds16(ebq + 16384 + t * 16, &cb[16384 + t * 16]);

    // ---- c0 quarter -> LDS (1 KB) ----
    if (t < 64) *(f32x4*)(c0l + t * 4) = *(const f32x4*)(c0 + q * 256 + t * 4);

    // ---- z -> fp8 A-frags; z^2 (published by quarter-0 blocks only) ----
    // wave wv = h-row (h0+wv); lane: pos nt*16+l15, channels kh*32+lq*8+p*4+j
    float part = 0.f;
    long bfr[4][2];
#pragma unroll
    for (int nt = 0; nt < 4; nt++) {
#pragma unroll
        for (int kh = 0; kh < 2; kh++) {
            unsigned int dw[2];
#pragma unroll
            for (int p = 0; p < 2; p++) {
                float f[4];
#pragma unroll
                for (int j = 0; j < 4; j++) {
                    f[j] = x[xbase + (size_t)(kh * 32 + lq * 8 + p * 4 + j) * 4096
                             + (size_t)wv * 64 + nt * 16 + l15];
                    part += f[j] * f[j];
                }
                unsigned int r = 0;
                r = __builtin_amdgcn_cvt_pk_fp8_f32(f[0], f[1], r, false);
                r = __builtin_amdgcn_cvt_pk_fp8_f32(f[2], f[3], r, true);
                dw[p] = r;
            }
            bfr[nt][kh] = (long)(((unsigned long long)dw[1] << 32) | dw[0]);
        }
    }
    __syncthreads();                             // DMA + c0l complete

    // ---- sweep 16 mt (this quarter), no barriers ----
    // banks (18*l15+2*lq)%32 -> 4 touches/bank (conflict floor, R14/R15: 0)
    unsigned int key[4] = {0u, 0u, 0u, 0u};
    const unsigned char* bbase = &cb[l15 * ROWB + lq * 8];
    const float* cbase = c0l + lq * 4;
    const int invq = 1023 - q * 256 - lq * 4;
#pragma unroll 8
    for (int mt = 0; mt < 16; mt++) {
        long a0 = *(const long*)(bbase + mt * 16 * ROWB);
        long a1 = *(const long*)(bbase + mt * 16 * ROWB + 32);
        f32x4 c0v = *(const f32x4*)(cbase + mt * 16);
        const int invm = invq - mt * 16;
#pragma unroll
        for (int nt = 0; nt < 4; nt++) {
            f32x4 acc = __builtin_amdgcn_mfma_f32_16x16x32_fp8_fp8(
                a0, bfr[nt][0], c0v, 0, 0, 0);
            acc = __builtin_amdgcn_mfma_f32_16x16x32_fp8_fp8(
                a1, bfr[nt][1], acc, 0, 0, 0);
            // D: col(l15)=pos-in-16-tile, row=(lq*4+r)=code-in-16-tile
            unsigned int k0 = (__float_as_uint(acc[0]) & 0xFFFFFC00u) | (unsigned int)(invm);
            unsigned int k1 = (__float_as_uint(acc[1]) & 0xFFFFFC00u) | (unsigned int)(invm - 1);
            unsigned int k2 = (__float_as_uint(acc[2]) & 0xFFFFFC00u) | (unsigned int)(invm - 2);
            unsigned int k3 = (__float_as_uint(acc[3]) & 0xFFFFFC00u) | (unsigned int)(invm - 3);
            key[nt] = umax(key[nt], umax(umax(k0, k1), umax(k2, k3)));
        }
    }

    // ---- reduce lq replicas; every lane ends with all 4 keys ----
#pragma unroll
    for (int nt = 0; nt < 4; nt++) {
        unsigned int k = key[nt];
        k = umax(k, (unsigned int)__shfl_xor((int)k, 16));
        k = umax(k, (unsigned int)__shfl_xor((int)k, 32));
        key[nt] = k;
    }

    // ---- own position (pos = lane, nt = lane>>4) via static selects ----
    unsigned int klo = (lane & 16) ? key[1] : key[0];
    unsigned int khi = (lane & 16) ? key[3] : key[2];
    unsigned int ks  = (lane & 32) ? khi : klo;
    atomicMax(&keys[tile * 256 + wv * 64 + lane], ks);   // coalesced, device-scope

    // ---- z^2 -> loss (quarter-0 blocks only; x covered exactly once) ----
    if (q == 0) {
#pragma unroll
        for (int off = 1; off < 64; off <<= 1) part += __shfl_xor(part, off);
        if (lane == 0) atomicAdd(loss, part * LOSS_SCALE);
    }
}

// ---- epilogue: keys -> idx -> gather embed -> z_q write + loss acc-part ----
// grid 1024 = 512 tiles x 2 channel-halves; 256 thr, thread = one position
__global__ void vq_out(
    const unsigned int* __restrict__ keys,
    const float* __restrict__ embed,
    float* __restrict__ out,
    float* __restrict__ loss) {

    const int t    = threadIdx.x;
    const int blk  = blockIdx.x;                 // 0..1023
    const int tile = blk >> 1, ch = blk & 1;
    const int b    = tile >> 4;
    const int h0   = (tile & 15) * 4;
    const int hh   = t >> 6, w = t & 63;

    const unsigned int k = keys[tile * 256 + t];
    const int idx = 1023 - (int)(k & 1023u);

    // loss acc-part: counted once per position (ch==0 blocks)
    if (ch == 0) {
        float la = -(1.f / 512.f) * __uint_as_float(k & 0xFFFFFC00u);
#pragma unroll
        for (int off = 1; off < 64; off <<= 1) la += __shfl_xor(la, off);
        // + 0.125 per position: 64 positions per wave -> +8
        if ((t & 63) == 0) atomicAdd(loss, (la + 8.0f) * LOSS_SCALE);
    }

    const int c0ch = ch * 32;
    const float* erow = embed + idx * 64 + c0ch;           // L2-hot gather
    float* orow = out + (size_t)b * 262144 + (size_t)(h0 + hh) * 64 + w
                + (size_t)c0ch * 4096;
#pragma unroll
    for (int c4 = 0; c4 < 8; c4++) {
        f32x4 ev = *(const f32x4*)(erow + c4 * 4);
#pragma unroll
        for (int j = 0; j < 4; j++)
            orow[(size_t)(c4 * 4 + j) * 4096] = ev[j];     // 256B contig/inst
    }
}

extern "C" void kernel_launch(void* const* d_in, const int* in_sizes, int n_in,
                              void* d_out, int out_size, void* d_ws, size_t ws_size,
                              hipStream_t stream) {
    const float* x     = (const float*)d_in[0];
    const float* embed = (const float*)d_in[1];
    unsigned int* keys = (unsigned int*)d_ws;                  // 512 KB
    unsigned char* eb  = (unsigned char*)d_ws + 524288;        // 72 KB (stride-72)
    float* c0          = (float*)((char*)d_ws + 524288 + 73728); // 4 KB
    float* out  = (float*)d_out;
    float* loss = out + TOTAL_ELEMS;

    hipMemsetAsync(keys, 0, 131072 * sizeof(unsigned int), stream);
    vq_prep<<<16, 256, 0, stream>>>(embed, eb, c0, loss);
    vq_sweep<<<2048, 256, 0, stream>>>(x, eb, c0, keys, loss);
    vq_out<<<1024, 256, 0, stream>>>(keys, embed, out, loss);
}